// Round 3
// baseline (408.563 us; speedup 1.0000x reference)
//
#include <hip/hip_runtime.h>
#include <hip/hip_bf16.h>
#include <math.h>

// x: (2, 192, 256, 256) f32 ; w_qkv: (192, 576) ; b_qkv: (576,)
// windows: 32x32 = 1024 per batch, 8x8=64 pixels each
// out: (2, 1024, 4, 64, 192) f32
#define NB   2
#define NC   192
#define HW   256
#define NWIN 1024
#define SHW  64
#define NDQ  192
#define WCOL 576

// ---------------- K1: window mean of x -> xmean[b][n][c] ----------------
__global__ __launch_bounds__(256) void k1_mean(const float* __restrict__ x,
                                               float* __restrict__ xmean) {
  int id = blockIdx.x * 256 + threadIdx.x;
  int n  = id & 1023;
  int c  = (id >> 10) % NC;
  int b  = id / (NC * NWIN);
  int wh = n >> 5, ww = n & 31;
  const float* p = x + (((size_t)(b * NC + c) * HW + wh * 8) * HW + ww * 8);
  double s = 0.0;
#pragma unroll
  for (int r = 0; r < 8; ++r) {
    float4 a = *(const float4*)(p + r * HW);
    float4 q = *(const float4*)(p + r * HW + 4);
    s += (double)a.x + a.y + a.z + a.w + q.x + q.y + q.z + q.w;
  }
  xmean[(size_t)(b * NWIN + n) * NC + c] = (float)(s * (1.0 / 64.0));
}

// ---------------- K2: q_win (scaled) and k_win^T ----------------
__global__ __launch_bounds__(192) void k2_qk(const float* __restrict__ xmean,
                                             const float* __restrict__ w,
                                             const float* __restrict__ bias,
                                             float* __restrict__ qw,
                                             float* __restrict__ kwT) {
  int b = blockIdx.y, n = blockIdx.x;
  int d = threadIdx.x;
  __shared__ float xs[NC];
  xs[d] = xmean[(size_t)(b * NWIN + n) * NC + d];
  __syncthreads();
  double aq = 0.0, ak = 0.0;
  for (int c = 0; c < NC; ++c) {
    double xc = (double)xs[c];
    aq += xc * (double)w[c * WCOL + d];
    ak += xc * (double)w[c * WCOL + NDQ + d];
  }
  const float scale = 0.0721687836487032f;
  float qv = (float)aq + bias[d];
  float kv = (float)ak + bias[NDQ + d];
  qw[(size_t)(b * NWIN + n) * NC + d] = qv * scale;
  kwT[(size_t)b * NC * NWIN + (size_t)d * NWIN + n] = kv;
}

// ---------------- K3: 8 logit rows per block + per-wave top-4 ----------------
__global__ __launch_bounds__(256) void k3_topk(const float* __restrict__ qw,
                                               const float* __restrict__ kwT,
                                               int* __restrict__ topk,
                                               int* __restrict__ counts) {
  int b = blockIdx.y, n0 = blockIdx.x * 8;
  int t = threadIdx.x;
  __shared__ float qs[8][NC];
  __shared__ float lg[8][NWIN];
#pragma unroll
  for (int i = 0; i < 6; ++i) {
    int l = i * 256 + t;
    int r = l / NC, c = l - r * NC;
    qs[r][c] = qw[(size_t)(b * NWIN + n0 + r) * NC + c];
  }
  __syncthreads();

  double acc[8][4];
#pragma unroll
  for (int r = 0; r < 8; ++r)
#pragma unroll
    for (int j = 0; j < 4; ++j) acc[r][j] = 0.0;

  const float* kb = kwT + (size_t)b * NC * NWIN;
#pragma unroll 2
  for (int c = 0; c < NC; ++c) {
    float4 kv = *(const float4*)(kb + (size_t)c * NWIN + t * 4);
    double k0 = (double)kv.x, k1 = (double)kv.y, k2 = (double)kv.z, k3 = (double)kv.w;
#pragma unroll
    for (int r = 0; r < 8; ++r) {
      double q = (double)qs[r][c];
      acc[r][0] += q * k0;
      acc[r][1] += q * k1;
      acc[r][2] += q * k2;
      acc[r][3] += q * k3;
    }
  }
#pragma unroll
  for (int r = 0; r < 8; ++r)
    *(float4*)&lg[r][t * 4] = make_float4((float)acc[r][0], (float)acc[r][1],
                                          (float)acc[r][2], (float)acc[r][3]);
  __syncthreads();

  int wave = t >> 6, lane = t & 63;
  for (int rr = 0; rr < 2; ++rr) {
    int r = wave * 2 + rr;
    float v4[4];
    int   i4[4];
#pragma unroll
    for (int j = 0; j < 4; ++j) { v4[j] = -INFINITY; i4[j] = 0x7fffffff; }
    for (int i = 0; i < 16; ++i) {
      int idx = i * 64 + lane;
      float v = lg[r][idx];
      if (v > v4[3] || (v == v4[3] && idx < i4[3])) {
        v4[3] = v; i4[3] = idx;
#pragma unroll
        for (int j = 3; j > 0; --j) {
          if (v4[j] > v4[j-1] || (v4[j] == v4[j-1] && i4[j] < i4[j-1])) {
            float tv = v4[j]; v4[j] = v4[j-1]; v4[j-1] = tv;
            int ti = i4[j]; i4[j] = i4[j-1]; i4[j-1] = ti;
          }
        }
      }
    }
    for (int m = 1; m < 64; m <<= 1) {
      float ov[4]; int oi[4];
#pragma unroll
      for (int j = 0; j < 4; ++j) { ov[j] = __shfl_xor(v4[j], m); oi[j] = __shfl_xor(i4[j], m); }
      float nv[4]; int ni[4];
      int ia = 0, ib = 0;
#pragma unroll
      for (int j = 0; j < 4; ++j) {
        bool ta = (v4[ia] > ov[ib]) || (v4[ia] == ov[ib] && i4[ia] < oi[ib]);
        if (ta) { nv[j] = v4[ia]; ni[j] = i4[ia]; ++ia; }
        else    { nv[j] = ov[ib]; ni[j] = oi[ib]; ++ib; }
      }
#pragma unroll
      for (int j = 0; j < 4; ++j) { v4[j] = nv[j]; i4[j] = ni[j]; }
    }
    if (lane == 0) {
      int n = n0 + r;
#pragma unroll
      for (int k = 0; k < 4; ++k) {
        topk[(size_t)(b * NWIN + n) * 4 + k] = i4[k];
        atomicAdd(&counts[b * NWIN + i4[k]], 1);
      }
    }
  }
}

// ---------------- K_scan ----------------
__global__ __launch_bounds__(1024) void k_scan(const int* __restrict__ counts,
                                               int* __restrict__ offs,
                                               int* __restrict__ cursor) {
  int b = blockIdx.x;
  int t = threadIdx.x;
  __shared__ int sd[1024];
  int v = counts[b * NWIN + t];
  sd[t] = v;
  __syncthreads();
  for (int s = 1; s < 1024; s <<= 1) {
    int add = (t >= s) ? sd[t - s] : 0;
    __syncthreads();
    sd[t] += add;
    __syncthreads();
  }
  int excl = sd[t] - v;
  offs[b * NWIN + t]   = excl;
  cursor[b * NWIN + t] = excl;
}

// ---------------- K_fill ----------------
__global__ __launch_bounds__(256) void k_fill(const int* __restrict__ topk,
                                              int* __restrict__ cursor,
                                              int* __restrict__ list) {
  int id = blockIdx.x * 256 + threadIdx.x;
  int b   = id >> 12;
  int rem = id & 4095;
  int m   = topk[b * 4096 + rem];
  int pos = atomicAdd(&cursor[b * NWIN + m], 1);
  list[b * 4096 + pos] = rem;
}

// ---------------- K4: 4 adjacent windows per block, f32 GEMM + scatter ----------------
__global__ __launch_bounds__(512) void k4_gemm(const float* __restrict__ x,
                                               const float* __restrict__ w,
                                               const float* __restrict__ bias,
                                               const int* __restrict__ counts,
                                               const int* __restrict__ offs,
                                               const int* __restrict__ list,
                                               float* __restrict__ out) {
  int b = blockIdx.y, g = blockIdx.x;   // g in [0,256)
  int m0 = g * 4;
  int wh = m0 >> 5, ww0 = m0 & 31;      // ww0 multiple of 4
  int t = threadIdx.x;

  __shared__ float4 Xs[2048];   // [c(32)][pos(64)] float4 -> 32 KB
  __shared__ float  Ws[6144];   // [c(32)][192]            -> 24 KB

  int cw0 = counts[b * NWIN + m0 + 0];
  int cw1 = counts[b * NWIN + m0 + 1];
  int cw2 = counts[b * NWIN + m0 + 2];
  int cw3 = counts[b * NWIN + m0 + 3];
  if ((cw0 | cw1 | cw2 | cw3) == 0) return;

  int dg = t & 7;       // 8 d-groups of 24 dims
  int pg = t >> 3;      // 64 pixel-quads (window = pg>>4, quad = pg&15)

  float acc[4][24];
#pragma unroll
  for (int j = 0; j < 24; ++j) {
    float bj = bias[384 + dg * 24 + j];
    acc[0][j] = bj; acc[1][j] = bj; acc[2][j] = bj; acc[3][j] = bj;
  }

  const float* xb = x + (size_t)b * NC * HW * HW + (size_t)(wh * 8) * HW + ww0 * 8;

  for (int cc = 0; cc < 6; ++cc) {
    // stage X chunk: 32c x 8r x 32w, rows are 128B-contiguous
#pragma unroll
    for (int i = 0; i < 4; ++i) {
      int l = i * 512 + t;
      int c  = l >> 6;
      int rr = (l >> 3) & 7;
      int w4 = l & 7;
      float4 v = *(const float4*)(xb + (size_t)(cc * 32 + c) * (HW * HW) + rr * HW + w4 * 4);
      int pos = ((w4 >> 1) & 3) * 16 + rr * 2 + (w4 & 1);  // group by window
      Xs[c * 64 + pos] = v;
    }
    // stage W chunk: 32c x 192d (V columns)
#pragma unroll
    for (int i = 0; i < 3; ++i) {
      int l = i * 512 + t;
      int c = l / 48, dq = l - c * 48;
      *(float4*)&Ws[c * NC + dq * 4] =
          *(const float4*)(w + (size_t)(cc * 32 + c) * WCOL + 2 * NDQ + dq * 4);
    }
    __syncthreads();

#pragma unroll 2
    for (int c = 0; c < 32; ++c) {
      float4 xv = Xs[c * 64 + pg];
      float wv[24];
#pragma unroll
      for (int j4 = 0; j4 < 6; ++j4)
        *(float4*)&wv[j4 * 4] = *(const float4*)&Ws[c * NC + dg * 24 + j4 * 4];
      float xf[4] = {xv.x, xv.y, xv.z, xv.w};
#pragma unroll
      for (int pi = 0; pi < 4; ++pi)
#pragma unroll
        for (int j = 0; j < 24; ++j)
          acc[pi][j] = fmaf(xf[pi], wv[j], acc[pi][j]);
    }
    __syncthreads();
  }

  // scatter: thread-groups (t>>7) own window wloc; selector loop is uniform per group
  int wloc = t >> 7;
  int cw[4] = {cw0, cw1, cw2, cw3};
  int cnt = cw[wloc];
  int off = offs[b * NWIN + m0 + wloc];
  int p_local = (pg & 15) * 4;
  const int* lp = list + b * 4096 + off;
  for (int s = 0; s < cnt; ++s) {
    int sel = lp[s];
    float* dst = out + (((size_t)(b * NWIN) + (sel >> 2)) * 4 + (sel & 3)) * (SHW * NC);
#pragma unroll
    for (int pi = 0; pi < 4; ++pi) {
      float* dp = dst + (size_t)(p_local + pi) * NC + dg * 24;
#pragma unroll
      for (int j4 = 0; j4 < 6; ++j4)
        *(float4*)(dp + j4 * 4) = make_float4(acc[pi][j4 * 4 + 0], acc[pi][j4 * 4 + 1],
                                              acc[pi][j4 * 4 + 2], acc[pi][j4 * 4 + 3]);
    }
  }
}

extern "C" void kernel_launch(void* const* d_in, const int* in_sizes, int n_in,
                              void* d_out, int out_size, void* d_ws, size_t ws_size,
                              hipStream_t stream) {
  const float* x    = (const float*)d_in[0];
  const float* w    = (const float*)d_in[1];
  const float* bias = (const float*)d_in[2];
  float* out = (float*)d_out;

  float* xmean = (float*)d_ws;
  float* qw    = xmean + 393216;
  float* kwT   = qw + 393216;
  int*   topk   = (int*)(kwT + 393216);
  int*   counts = topk + 8192;
  int*   offs   = counts + 2048;
  int*   cursor = offs + 2048;
  int*   list   = cursor + 2048;

  hipMemsetAsync(counts, 0, 2048 * sizeof(int), stream);
  k1_mean<<<1536, 256, 0, stream>>>(x, xmean);
  k2_qk<<<dim3(1024, 2), 192, 0, stream>>>(xmean, w, bias, qw, kwT);
  k3_topk<<<dim3(128, 2), 256, 0, stream>>>(qw, kwT, topk, counts);
  k_scan<<<2, 1024, 0, stream>>>(counts, offs, cursor);
  k_fill<<<32, 256, 0, stream>>>(topk, cursor, list);
  k4_gemm<<<dim3(256, 2), 512, 0, stream>>>(x, w, bias, counts, offs, list, out);
}

// Round 4
// 253.525 us; speedup vs baseline: 1.6115x; 1.6115x over previous
//
#include <hip/hip_runtime.h>
#include <hip/hip_bf16.h>
#include <math.h>

// x: (2, 192, 256, 256) f32 ; w_qkv: (192, 576) ; b_qkv: (576,)
// windows: 32x32 = 1024 per batch, 8x8=64 pixels each
// out: (2, 1024, 4, 64, 192) f32
#define NB   2
#define NC   192
#define HW   256
#define NWIN 1024
#define SHW  64
#define NDQ  192
#define WCOL 576

typedef short bf16x8 __attribute__((ext_vector_type(8)));
typedef float f32x4  __attribute__((ext_vector_type(4)));

__device__ inline unsigned int bf16pack(float a, float b) {
  unsigned int ua = __builtin_bit_cast(unsigned int, a);
  ua += 0x7fffu + ((ua >> 16) & 1u);
  unsigned int ub = __builtin_bit_cast(unsigned int, b);
  ub += 0x7fffu + ((ub >> 16) & 1u);
  return (ua >> 16) | (ub & 0xffff0000u);
}

// ---------------- K0: precompute WvT bf16 [d][c] ----------------
__global__ __launch_bounds__(256) void k0_wvt(const float* __restrict__ w,
                                              unsigned short* __restrict__ wvt) {
  int id = blockIdx.x * 256 + threadIdx.x;   // 192*192 = 36864
  int d = id / NC, c = id - d * NC;
  unsigned int u = __builtin_bit_cast(unsigned int, w[c * WCOL + 2 * NDQ + d]);
  u += 0x7fffu + ((u >> 16) & 1u);
  wvt[d * NC + c] = (unsigned short)(u >> 16);
}

// ---------------- K1: window mean of x -> xmean[b][n][c] ----------------
__global__ __launch_bounds__(256) void k1_mean(const float* __restrict__ x,
                                               float* __restrict__ xmean) {
  int id = blockIdx.x * 256 + threadIdx.x;
  int n  = id & 1023;
  int c  = (id >> 10) % NC;
  int b  = id / (NC * NWIN);
  int wh = n >> 5, ww = n & 31;
  const float* p = x + (((size_t)(b * NC + c) * HW + wh * 8) * HW + ww * 8);
  double s = 0.0;
#pragma unroll
  for (int r = 0; r < 8; ++r) {
    float4 a = *(const float4*)(p + r * HW);
    float4 q = *(const float4*)(p + r * HW + 4);
    s += (double)a.x + a.y + a.z + a.w + q.x + q.y + q.z + q.w;
  }
  xmean[(size_t)(b * NWIN + n) * NC + c] = (float)(s * (1.0 / 64.0));
}

// ---------------- K2: q_win (scaled) and k_win^T ----------------
__global__ __launch_bounds__(192) void k2_qk(const float* __restrict__ xmean,
                                             const float* __restrict__ w,
                                             const float* __restrict__ bias,
                                             float* __restrict__ qw,
                                             float* __restrict__ kwT) {
  int b = blockIdx.y, n = blockIdx.x;
  int d = threadIdx.x;
  __shared__ float xs[NC];
  xs[d] = xmean[(size_t)(b * NWIN + n) * NC + d];
  __syncthreads();
  double aq = 0.0, ak = 0.0;
  for (int c = 0; c < NC; ++c) {
    double xc = (double)xs[c];
    aq += xc * (double)w[c * WCOL + d];
    ak += xc * (double)w[c * WCOL + NDQ + d];
  }
  const float scale = 0.0721687836487032f;
  float qv = (float)aq + bias[d];
  float kv = (float)ak + bias[NDQ + d];
  qw[(size_t)(b * NWIN + n) * NC + d] = qv * scale;
  kwT[(size_t)b * NC * NWIN + (size_t)d * NWIN + n] = kv;
}

// ---------------- K3: 8 logit rows per block + per-wave top-4 ----------------
__global__ __launch_bounds__(256) void k3_topk(const float* __restrict__ qw,
                                               const float* __restrict__ kwT,
                                               int* __restrict__ topk,
                                               int* __restrict__ counts) {
  int b = blockIdx.y, n0 = blockIdx.x * 8;
  int t = threadIdx.x;
  __shared__ float qs[8][NC];
  __shared__ float lg[8][NWIN];
#pragma unroll
  for (int i = 0; i < 6; ++i) {
    int l = i * 256 + t;
    int r = l / NC, c = l - r * NC;
    qs[r][c] = qw[(size_t)(b * NWIN + n0 + r) * NC + c];
  }
  __syncthreads();

  double acc[8][4];
#pragma unroll
  for (int r = 0; r < 8; ++r)
#pragma unroll
    for (int j = 0; j < 4; ++j) acc[r][j] = 0.0;

  const float* kb = kwT + (size_t)b * NC * NWIN;
#pragma unroll 2
  for (int c = 0; c < NC; ++c) {
    float4 kv = *(const float4*)(kb + (size_t)c * NWIN + t * 4);
    double k0 = (double)kv.x, k1 = (double)kv.y, k2 = (double)kv.z, k3 = (double)kv.w;
#pragma unroll
    for (int r = 0; r < 8; ++r) {
      double q = (double)qs[r][c];
      acc[r][0] += q * k0;
      acc[r][1] += q * k1;
      acc[r][2] += q * k2;
      acc[r][3] += q * k3;
    }
  }
#pragma unroll
  for (int r = 0; r < 8; ++r)
    *(float4*)&lg[r][t * 4] = make_float4((float)acc[r][0], (float)acc[r][1],
                                          (float)acc[r][2], (float)acc[r][3]);
  __syncthreads();

  int wave = t >> 6, lane = t & 63;
  for (int rr = 0; rr < 2; ++rr) {
    int r = wave * 2 + rr;
    float v4[4];
    int   i4[4];
#pragma unroll
    for (int j = 0; j < 4; ++j) { v4[j] = -INFINITY; i4[j] = 0x7fffffff; }
    for (int i = 0; i < 16; ++i) {
      int idx = i * 64 + lane;
      float v = lg[r][idx];
      if (v > v4[3] || (v == v4[3] && idx < i4[3])) {
        v4[3] = v; i4[3] = idx;
#pragma unroll
        for (int j = 3; j > 0; --j) {
          if (v4[j] > v4[j-1] || (v4[j] == v4[j-1] && i4[j] < i4[j-1])) {
            float tv = v4[j]; v4[j] = v4[j-1]; v4[j-1] = tv;
            int ti = i4[j]; i4[j] = i4[j-1]; i4[j-1] = ti;
          }
        }
      }
    }
    for (int m = 1; m < 64; m <<= 1) {
      float ov[4]; int oi[4];
#pragma unroll
      for (int j = 0; j < 4; ++j) { ov[j] = __shfl_xor(v4[j], m); oi[j] = __shfl_xor(i4[j], m); }
      float nv[4]; int ni[4];
      int ia = 0, ib = 0;
#pragma unroll
      for (int j = 0; j < 4; ++j) {
        bool ta = (v4[ia] > ov[ib]) || (v4[ia] == ov[ib] && i4[ia] < oi[ib]);
        if (ta) { nv[j] = v4[ia]; ni[j] = i4[ia]; ++ia; }
        else    { nv[j] = ov[ib]; ni[j] = oi[ib]; ++ib; }
      }
#pragma unroll
      for (int j = 0; j < 4; ++j) { v4[j] = nv[j]; i4[j] = ni[j]; }
    }
    if (lane == 0) {
      int n = n0 + r;
#pragma unroll
      for (int k = 0; k < 4; ++k) {
        topk[(size_t)(b * NWIN + n) * 4 + k] = i4[k];
        atomicAdd(&counts[b * NWIN + i4[k]], 1);
      }
    }
  }
}

// ---------------- K_scan ----------------
__global__ __launch_bounds__(1024) void k_scan(const int* __restrict__ counts,
                                               int* __restrict__ offs,
                                               int* __restrict__ cursor) {
  int b = blockIdx.x;
  int t = threadIdx.x;
  __shared__ int sd[1024];
  int v = counts[b * NWIN + t];
  sd[t] = v;
  __syncthreads();
  for (int s = 1; s < 1024; s <<= 1) {
    int add = (t >= s) ? sd[t - s] : 0;
    __syncthreads();
    sd[t] += add;
    __syncthreads();
  }
  int excl = sd[t] - v;
  offs[b * NWIN + t]   = excl;
  cursor[b * NWIN + t] = excl;
}

// ---------------- K_fill ----------------
__global__ __launch_bounds__(256) void k_fill(const int* __restrict__ topk,
                                              int* __restrict__ cursor,
                                              int* __restrict__ list) {
  int id = blockIdx.x * 256 + threadIdx.x;
  int b   = id >> 12;
  int rem = id & 4095;
  int m   = topk[b * 4096 + rem];
  int pos = atomicAdd(&cursor[b * NWIN + m], 1);
  list[b * 4096 + pos] = rem;
}

// ---------------- K4: MFMA bf16 V-GEMM, 4 adjacent windows/block, scatter ----------------
// 1024 threads = 16 waves; wave wv: win = wv>>2, d-quarter dq = wv&3 (48 dims).
// Xs LDS: [win][p][128B row], bf16 pairs, XOR-swizzled (^((p&7)<<4) on byte addr).
__global__ __launch_bounds__(1024) void k4_mfma(const float* __restrict__ x,
                                                const unsigned short* __restrict__ wvt,
                                                const float* __restrict__ bias,
                                                const int* __restrict__ counts,
                                                const int* __restrict__ offs,
                                                const int* __restrict__ list,
                                                float* __restrict__ out) {
  int b = blockIdx.y, g = blockIdx.x;   // g in [0,256)
  int m0 = g * 4;
  int wh = m0 >> 5, ww0 = m0 & 31;
  int t = threadIdx.x;

  __shared__ unsigned short Xs[16384];  // 32 KB: 4 win * 64 p * 128B

  int c0 = counts[b * NWIN + m0 + 0];
  int c1 = counts[b * NWIN + m0 + 1];
  int c2 = counts[b * NWIN + m0 + 2];
  int c3 = counts[b * NWIN + m0 + 3];
  if ((c0 | c1 | c2 | c3) == 0) return;

  int L = t & 63, wv = t >> 6;
  int win = wv >> 2, dq = wv & 3;
  int col = L & 15, kg = L >> 4;

  // acc init with V-bias (depends only on output col d)
  f32x4 acc[4][3];
#pragma unroll
  for (int dt = 0; dt < 3; ++dt) {
    float bv = bias[2 * NDQ + dq * 48 + dt * 16 + col];
    f32x4 bi = {bv, bv, bv, bv};
#pragma unroll
    for (int pt = 0; pt < 4; ++pt) acc[pt][dt] = bi;
  }

  // staging decomposition: t = gi*16 + cp ; gi = r*8 + w4
  int cp = t & 15, gi = t >> 4;
  int r = gi >> 3, w4 = gi & 7;
  int winS = w4 >> 1;
  int pS = r * 8 + (w4 & 1) * 4;
  const float* xb = x + (size_t)(b * NC) * (HW * HW) + (size_t)(wh * 8 + r) * HW + ww0 * 8 + w4 * 4;

  for (int cc = 0; cc < 6; ++cc) {
    // stage: 2 channel planes (cp*2, cp*2+1), 4 pixels each -> 4 packed dwords
    const float* pl = xb + (size_t)(cc * 32 + cp * 2) * (HW * HW);
    float4 va = *(const float4*)pl;
    float4 vb = *(const float4*)(pl + HW * HW);
    float fa[4] = {va.x, va.y, va.z, va.w};
    float fb[4] = {vb.x, vb.y, vb.z, vb.w};
#pragma unroll
    for (int i = 0; i < 4; ++i) {
      int p = pS + i;
      unsigned int pk = bf16pack(fa[i], fb[i]);
      *(unsigned int*)((char*)Xs + (winS * 8192 + p * 128 + ((cp * 4) ^ ((p & 7) << 4)))) = pk;
    }
    __syncthreads();

    // B fragments for this K-chunk, from L2-resident WvT bf16 [d][c]
    bf16x8 Bf[3];
#pragma unroll
    for (int dt = 0; dt < 3; ++dt)
      Bf[dt] = *(const bf16x8*)(wvt + (size_t)(dq * 48 + dt * 16 + col) * NC + cc * 32 + kg * 8);

#pragma unroll
    for (int pt = 0; pt < 4; ++pt) {
      int p = pt * 16 + col;
      bf16x8 Af = *(const bf16x8*)((const char*)Xs +
                    (win * 8192 + p * 128 + ((kg * 16) ^ ((p & 7) << 4))));
      acc[pt][0] = __builtin_amdgcn_mfma_f32_16x16x32_bf16(Af, Bf[0], acc[pt][0], 0, 0, 0);
      acc[pt][1] = __builtin_amdgcn_mfma_f32_16x16x32_bf16(Af, Bf[1], acc[pt][1], 0, 0, 0);
      acc[pt][2] = __builtin_amdgcn_mfma_f32_16x16x32_bf16(Af, Bf[2], acc[pt][2], 0, 0, 0);
    }
    __syncthreads();
  }

  // scatter from registers: D layout col=lane&15, row=(lane>>4)*4+reg
  int cw4[4] = {c0, c1, c2, c3};
  int cnt = cw4[win];
  int off = offs[b * NWIN + m0 + win];
  const int* lp = list + b * 4096 + off;
  int dcol = dq * 48 + col;
  for (int s = 0; s < cnt; ++s) {
    int sel = lp[s];
    float* dst = out + ((size_t)(b * NWIN + (sel >> 2)) * 4 + (sel & 3)) * (SHW * NC) + dcol;
#pragma unroll
    for (int pt = 0; pt < 4; ++pt) {
#pragma unroll
      for (int rr = 0; rr < 4; ++rr) {
        float* dp = dst + (size_t)(pt * 16 + kg * 4 + rr) * NC;
        dp[0]  = acc[pt][0][rr];
        dp[16] = acc[pt][1][rr];
        dp[32] = acc[pt][2][rr];
      }
    }
  }
}

extern "C" void kernel_launch(void* const* d_in, const int* in_sizes, int n_in,
                              void* d_out, int out_size, void* d_ws, size_t ws_size,
                              hipStream_t stream) {
  const float* x    = (const float*)d_in[0];
  const float* w    = (const float*)d_in[1];
  const float* bias = (const float*)d_in[2];
  float* out = (float*)d_out;

  float* xmean = (float*)d_ws;
  float* qw    = xmean + 393216;
  float* kwT   = qw + 393216;
  int*   topk   = (int*)(kwT + 393216);
  int*   counts = topk + 8192;
  int*   offs   = counts + 2048;
  int*   cursor = offs + 2048;
  int*   list   = cursor + 2048;
  unsigned short* wvt = (unsigned short*)(list + 8192);  // 192*192 bf16

  hipMemsetAsync(counts, 0, 2048 * sizeof(int), stream);
  k0_wvt<<<144, 256, 0, stream>>>(w, wvt);
  k1_mean<<<1536, 256, 0, stream>>>(x, xmean);
  k2_qk<<<dim3(1024, 2), 192, 0, stream>>>(xmean, w, bias, qw, kwT);
  k3_topk<<<dim3(128, 2), 256, 0, stream>>>(qw, kwT, topk, counts);
  k_scan<<<2, 1024, 0, stream>>>(counts, offs, cursor);
  k_fill<<<32, 256, 0, stream>>>(topk, cursor, list);
  k4_mfma<<<dim3(256, 2), 1024, 0, stream>>>(x, wvt, bias, counts, offs, list, out);
}